// Round 5
// baseline (240.881 us; speedup 1.0000x reference)
//
#include <hip/hip_runtime.h>
#include <math.h>

#define SEQ   3000
#define FDIM  64
// 999 sequential steps = 111 groups x 9 steps.
// ILP: each thread advances TWO independent (b,f) chains (b and b+64).
// 64 blocks x 64 threads; wall time = per-wave time, so fewer CUs is free.

// Branchless gelu, exact-erf formulation (identical to R3; absmax 0.0625):
//   gelu(x) = relu(x) - 0.5*|x|*erfc(|x|/sqrt(2))
//   erfc via Abramowitz-Stegun 7.1.26 (|abs err| <= 1.5e-7), t = 1/(1+p*u)
__device__ __forceinline__ float gelu_f(float v) {
    const float ISQRT2 = 0.70710678118654752440f;
    float u = fabsf(v) * ISQRT2;
    float d = fmaf(0.3275911f, u, 1.0f);
    float r = __builtin_amdgcn_rcpf(d);
    r = r * fmaf(-d, r, 2.0f);                 // one Newton step
    float p = fmaf(1.061405429f, r, -1.453152027f);
    p = fmaf(p, r, 1.421413741f);
    p = fmaf(p, r, -0.284496736f);
    p = fmaf(p, r, 0.254829592f);
    p = p * r;                                 // P(t)*t
    float ex = __expf(-u * u);
    float er = p * ex;                         // erfc(u)
    float relu = fmaxf(v, 0.0f);
    return fmaf(-0.5f * fabsf(v), er, relu);
}

// Named scalars: nothing indexable -> nothing demotes to scratch; loads are
// loop-carried (consumed across the ping-pong) so they can't be sunk.
#define DECL27(p) float p##0,p##1,p##2,p##3,p##4,p##5,p##6,p##7,p##8,p##9,    \
    p##10,p##11,p##12,p##13,p##14,p##15,p##16,p##17,p##18,p##19,p##20,p##21,  \
    p##22,p##23,p##24,p##25,p##26

#define BUF(p) p##0,p##1,p##2,p##3,p##4,p##5,p##6,p##7,p##8,p##9,p##10,p##11, \
    p##12,p##13,p##14,p##15,p##16,p##17,p##18,p##19,p##20,p##21,p##22,p##23,  \
    p##24,p##25,p##26

#define LOADG_I(ptr, y0,y1,y2,y3,y4,y5,y6,y7,y8,y9,y10,y11,y12,y13,y14,y15,   \
                y16,y17,y18,y19,y20,y21,y22,y23,y24,y25,y26)                   \
    do {                                                                       \
        y0  = ptr[ 0*FDIM]; y1  = ptr[ 1*FDIM]; y2  = ptr[ 2*FDIM];           \
        y3  = ptr[ 3*FDIM]; y4  = ptr[ 4*FDIM]; y5  = ptr[ 5*FDIM];           \
        y6  = ptr[ 6*FDIM]; y7  = ptr[ 7*FDIM]; y8  = ptr[ 8*FDIM];           \
        y9  = ptr[ 9*FDIM]; y10 = ptr[10*FDIM]; y11 = ptr[11*FDIM];           \
        y12 = ptr[12*FDIM]; y13 = ptr[13*FDIM]; y14 = ptr[14*FDIM];           \
        y15 = ptr[15*FDIM]; y16 = ptr[16*FDIM]; y17 = ptr[17*FDIM];           \
        y18 = ptr[18*FDIM]; y19 = ptr[19*FDIM]; y20 = ptr[20*FDIM];           \
        y21 = ptr[21*FDIM]; y22 = ptr[22*FDIM]; y23 = ptr[23*FDIM];           \
        y24 = ptr[24*FDIM]; y25 = ptr[25*FDIM]; y26 = ptr[26*FDIM];           \
        ptr += 27 * FDIM;                                                      \
    } while (0)
#define LOADG(ptr, ...) LOADG_I(ptr, __VA_ARGS__)

// one step of BOTH chains, interleaved at source level (6 independent gelus)
#define PAIR(k, u0, u1, u2, v0, v1, v2)                                        \
    do {                                                                       \
        float a0 = fmaf(s02, w02, fmaf(s01, w01, fmaf(s00, w00, q0)));         \
        float c0 = fmaf(s12, w02, fmaf(s11, w01, fmaf(s10, w00, q0)));         \
        float a1 = fmaf(s02, w12, fmaf(s01, w11, fmaf(s00, w10, q1)));         \
        float c1 = fmaf(s12, w12, fmaf(s11, w11, fmaf(s10, w10, q1)));         \
        float a2 = fmaf(s02, w22, fmaf(s01, w21, fmaf(s00, w20, q2)));         \
        float c2 = fmaf(s12, w22, fmaf(s11, w21, fmaf(s10, w20, q2)));         \
        s00 = gelu_f(a0) + u0;  s10 = gelu_f(c0) + v0;                         \
        s01 = gelu_f(a1) + u1;  s11 = gelu_f(c1) + v1;                         \
        s02 = gelu_f(a2) + u2;  s12 = gelu_f(c2) + v2;                         \
        oc0[(3*(k)+0)*FDIM] = s00;  oc1[(3*(k)+0)*FDIM] = s10;                 \
        oc0[(3*(k)+1)*FDIM] = s01;  oc1[(3*(k)+1)*FDIM] = s11;                 \
        oc0[(3*(k)+2)*FDIM] = s02;  oc1[(3*(k)+2)*FDIM] = s12;                 \
    } while (0)

#define COMPUTE2_I(y0,y1,y2,y3,y4,y5,y6,y7,y8,y9,y10,y11,y12,y13,y14,y15,y16, \
                   y17,y18,y19,y20,y21,y22,y23,y24,y25,y26,                    \
                   z0,z1,z2,z3,z4,z5,z6,z7,z8,z9,z10,z11,z12,z13,z14,z15,z16, \
                   z17,z18,z19,z20,z21,z22,z23,z24,z25,z26)                    \
    do {                                                                       \
        PAIR(0, y0,  y1,  y2 , z0,  z1,  z2 );                                 \
        PAIR(1, y3,  y4,  y5 , z3,  z4,  z5 );                                 \
        PAIR(2, y6,  y7,  y8 , z6,  z7,  z8 );                                 \
        PAIR(3, y9,  y10, y11, z9,  z10, z11);                                 \
        PAIR(4, y12, y13, y14, z12, z13, z14);                                 \
        PAIR(5, y15, y16, y17, z15, z16, z17);                                 \
        PAIR(6, y18, y19, y20, z18, z19, z20);                                 \
        PAIR(7, y21, y22, y23, z21, z22, z23);                                 \
        PAIR(8, y24, y25, y26, z24, z25, z26);                                 \
        oc0 += 27 * FDIM;  oc1 += 27 * FDIM;                                   \
    } while (0)
// variadic trampoline: forces BUF(...) to expand BEFORE COMPUTE2_I collects
// its 54 arguments (commas from an argument's own expansion never split args)
#define COMPUTE2_X(...) COMPUTE2_I(__VA_ARGS__)
#define COMPUTE2(A_, B_) COMPUTE2_X(BUF(A_), BUF(B_))

__global__ __launch_bounds__(64, 1) void scan_kernel(
    const float* __restrict__ x,
    const float* __restrict__ w,
    const float* __restrict__ bias,
    float* __restrict__ out)
{
    const int blk = blockIdx.x;    // 64 blocks; chains b=blk and b=blk+64
    const int f = threadIdx.x;

    const float w00 = w[0], w01 = w[1], w02 = w[2];
    const float w10 = w[3], w11 = w[4], w12 = w[5];
    const float w20 = w[6], w21 = w[7], w22 = w[8];
    const float q0 = bias[0], q1 = bias[1], q2 = bias[2];

    const float* __restrict__ xp0 = x   + (size_t)blk        * (SEQ * FDIM) + f;
    const float* __restrict__ xp1 = x   + (size_t)(blk + 64) * (SEQ * FDIM) + f;
    float*       __restrict__ op0 = out + (size_t)blk        * (SEQ * FDIM) + f;
    float*       __restrict__ op1 = out + (size_t)(blk + 64) * (SEQ * FDIM) + f;

    float s00 = xp0[0*FDIM], s01 = xp0[1*FDIM], s02 = xp0[2*FDIM];
    float s10 = xp1[0*FDIM], s11 = xp1[1*FDIM], s12 = xp1[2*FDIM];
    op0[0*FDIM] = s00; op0[1*FDIM] = s01; op0[2*FDIM] = s02;
    op1[0*FDIM] = s10; op1[1*FDIM] = s11; op1[2*FDIM] = s12;

    const float* xc0 = xp0 + 3 * FDIM;
    const float* xc1 = xp1 + 3 * FDIM;
    float*       oc0 = op0 + 3 * FDIM;
    float*       oc1 = op1 + 3 * FDIM;

    DECL27(A0); DECL27(B0); DECL27(A1); DECL27(B1);

    // prologue: group 0 for both chains
    LOADG(xc0, BUF(A0)); LOADG(xc1, BUF(A1));

    // double-buffered: 55 iterations x 2 groups = groups 0..109 computed,
    // 1..110 loaded; prefetch distance = 1 group = 9 step-pairs (~3000 cyc)
    #pragma unroll 1
    for (int t = 0; t < 55; ++t) {
        LOADG(xc0, BUF(B0)); LOADG(xc1, BUF(B1));
        COMPUTE2(A0, A1);
        LOADG(xc0, BUF(A0)); LOADG(xc1, BUF(A1));
        COMPUTE2(B0, B1);
    }
    // tail: group 110 (already in A)
    COMPUTE2(A0, A1);
}

extern "C" void kernel_launch(void* const* d_in, const int* in_sizes, int n_in,
                              void* d_out, int out_size, void* d_ws, size_t ws_size,
                              hipStream_t stream) {
    const float* x    = (const float*)d_in[0];
    const float* w    = (const float*)d_in[1];
    const float* bias = (const float*)d_in[2];
    float* out        = (float*)d_out;

    hipLaunchKernelGGL(scan_kernel, dim3(64), dim3(FDIM), 0, stream,
                       x, w, bias, out);
}

// Round 6
// 135.997 us; speedup vs baseline: 1.7712x; 1.7712x over previous
//
#include <hip/hip_runtime.h>
#include <math.h>

#define SEQ   3000
#define FDIM  64
// 999 sequential steps = 111 groups (g0..g110) x 9 steps.
// 128 blocks x 64 threads, one (b,f) chain per lane. ALL vmem is inline asm:
// prefetch loads 1 group ahead, counted s_waitcnt vmcnt(N) (never 0 in loop),
// asm stores from a double-banked rotating output file (reuse distance 2
// groups > retirement horizon, proven by the vmcnt(54) group-boundary wait).

// Branchless gelu: gelu(v) = relu(v) - |v| * [0.5*erfc(|v|/sqrt(2))]
// 0.5*erfc via halved Abramowitz-Stegun 7.1.26 coefficients, Estrin form,
// native v_rcp (no Newton: ~1ulp << 1.5e-7 formula error).
__device__ __forceinline__ float gelu_f(float v) {
    const float B1 =  0.127414796f;    // 0.5*0.254829592
    const float B2 = -0.142248368f;    // 0.5*-0.284496736
    const float B3 =  0.7107068705f;   // 0.5*1.421413741
    const float B4 = -0.7265760135f;   // 0.5*-1.453152027
    const float B5 =  0.5307027145f;   // 0.5*1.061405429
    float av = fabsf(v);
    float u  = av * 0.70710678118654752440f;
    float d  = fmaf(0.3275911f, u, 1.0f);
    float r  = __builtin_amdgcn_rcpf(d);
    float c01 = fmaf(B2, r, B1);
    float c23 = fmaf(B4, r, B3);
    float r2  = r * r;
    float c03 = fmaf(c23, r2, c01);
    float r4  = r2 * r2;
    float p   = fmaf(B5, r4, c03);
    float pr  = p * r;
    float ex  = __expf(-(u * u));
    float er  = pr * ex;               // = 0.5*erfc(u)
    return fmaf(-av, er, fmaxf(v, 0.0f));
}

#define DECL27(p)  float p##0,p##1,p##2,p##3,p##4,p##5,p##6,p##7,p##8,p##9,   \
    p##10,p##11,p##12,p##13,p##14,p##15,p##16,p##17,p##18,p##19,p##20,p##21,  \
    p##22,p##23,p##24,p##25,p##26
#define DECL27Z(p) float p##0=0,p##1=0,p##2=0,p##3=0,p##4=0,p##5=0,p##6=0,    \
    p##7=0,p##8=0,p##9=0,p##10=0,p##11=0,p##12=0,p##13=0,p##14=0,p##15=0,     \
    p##16=0,p##17=0,p##18=0,p##19=0,p##20=0,p##21=0,p##22=0,p##23=0,p##24=0,  \
    p##25=0,p##26=0

#define TOUCH27(P) "+v"(P##0),"+v"(P##1),"+v"(P##2),"+v"(P##3),"+v"(P##4),    \
    "+v"(P##5),"+v"(P##6),"+v"(P##7),"+v"(P##8),"+v"(P##9),"+v"(P##10),       \
    "+v"(P##11),"+v"(P##12),"+v"(P##13),"+v"(P##14),"+v"(P##15),"+v"(P##16),  \
    "+v"(P##17),"+v"(P##18),"+v"(P##19),"+v"(P##20),"+v"(P##21),"+v"(P##22),  \
    "+v"(P##23),"+v"(P##24),"+v"(P##25),"+v"(P##26)

#define PF1(dst, p, OFF)                                                      \
    asm volatile("global_load_dword %0, %1, off offset:" #OFF                 \
                 : "=v"(dst) : "v"(p) : "memory")
#define ST1(val, p, OFF)                                                      \
    asm volatile("global_store_dword %0, %1, off offset:" #OFF                \
                 :: "v"(p), "v"(val) : "memory")

// 27 loads of one group; xc advances 9 rows (2304 B) per 9 loads so every
// offset immediate stays < 4096.
#define PF27(P) do {                                                          \
    PF1(P##0,  xc, 0);    PF1(P##1,  xc, 256);  PF1(P##2,  xc, 512);          \
    PF1(P##3,  xc, 768);  PF1(P##4,  xc, 1024); PF1(P##5,  xc, 1280);         \
    PF1(P##6,  xc, 1536); PF1(P##7,  xc, 1792); PF1(P##8,  xc, 2048);         \
    xc += 9 * FDIM;                                                           \
    PF1(P##9,  xc, 0);    PF1(P##10, xc, 256);  PF1(P##11, xc, 512);          \
    PF1(P##12, xc, 768);  PF1(P##13, xc, 1024); PF1(P##14, xc, 1280);         \
    PF1(P##15, xc, 1536); PF1(P##16, xc, 1792); PF1(P##17, xc, 2048);         \
    xc += 9 * FDIM;                                                           \
    PF1(P##18, xc, 0);    PF1(P##19, xc, 256);  PF1(P##20, xc, 512);          \
    PF1(P##21, xc, 768);  PF1(P##22, xc, 1024); PF1(P##23, xc, 1280);         \
    PF1(P##24, xc, 1536); PF1(P##25, xc, 1792); PF1(P##26, xc, 2048);         \
    xc += 9 * FDIM;                                                           \
} while (0)

// counted wait: P = load buffer about to be consumed (dataflow tie so its
// consumers cannot hoist above the wait); O = output bank about to be
// overwritten (its stores are proven retired by this wait's count).
#define WAITVM(Nlit, P, O) do {                                               \
    asm volatile("s_waitcnt vmcnt(" #Nlit ")" : TOUCH27(P) : : "memory");     \
    asm volatile("" : TOUCH27(O) : : "memory");                               \
    __builtin_amdgcn_sched_barrier(0);                                        \
} while (0)

// one scan step: state (x,y,z) -> outputs O##i0..i2, asm-stored at oc+imm
#define GSTEP(O, i0, i1, i2, x, y, z, F0, F1, F2, u0, u1, u2)                 \
    do {                                                                      \
        float a0_ = fmaf(z, w02, fmaf(y, w01, fmaf(x, w00, q0)));             \
        float a1_ = fmaf(z, w12, fmaf(y, w11, fmaf(x, w10, q1)));             \
        float a2_ = fmaf(z, w22, fmaf(y, w21, fmaf(x, w20, q2)));             \
        O##i0 = gelu_f(a0_) + u0;                                             \
        O##i1 = gelu_f(a1_) + u1;                                             \
        O##i2 = gelu_f(a2_) + u2;                                             \
        ST1(O##i0, oc, F0);                                                   \
        ST1(O##i1, oc, F1);                                                   \
        ST1(O##i2, oc, F2);                                                   \
    } while (0)

// one group of 9 steps; state flows sa,sb,sc -> O##24,O##25,O##26
#define COMPUTE_GRP(P, O, sa, sb, sc) do {                                    \
    GSTEP(O, 0, 1, 2,   sa,    sb,    sc,    0, 256, 512,      P##0,  P##1,  P##2);  \
    GSTEP(O, 3, 4, 5,   O##0,  O##1,  O##2,  768, 1024, 1280,  P##3,  P##4,  P##5);  \
    GSTEP(O, 6, 7, 8,   O##3,  O##4,  O##5,  1536, 1792, 2048, P##6,  P##7,  P##8);  \
    oc += 9 * FDIM;                                                           \
    GSTEP(O, 9, 10, 11, O##6,  O##7,  O##8,  0, 256, 512,      P##9,  P##10, P##11); \
    GSTEP(O, 12, 13, 14, O##9,  O##10, O##11, 768, 1024, 1280, P##12, P##13, P##14); \
    GSTEP(O, 15, 16, 17, O##12, O##13, O##14, 1536, 1792, 2048, P##15, P##16, P##17);\
    oc += 9 * FDIM;                                                           \
    GSTEP(O, 18, 19, 20, O##15, O##16, O##17, 0, 256, 512,     P##18, P##19, P##20); \
    GSTEP(O, 21, 22, 23, O##18, O##19, O##20, 768, 1024, 1280, P##21, P##22, P##23); \
    GSTEP(O, 24, 25, 26, O##21, O##22, O##23, 1536, 1792, 2048, P##24, P##25, P##26);\
    oc += 9 * FDIM;                                                           \
} while (0)

__global__ __launch_bounds__(64, 1) void scan_kernel(
    const float* __restrict__ x,
    const float* __restrict__ w,
    const float* __restrict__ bias,
    float* __restrict__ out)
{
    const int b = blockIdx.x;
    const int f = threadIdx.x;

    const float w00 = w[0], w01 = w[1], w02 = w[2];
    const float w10 = w[3], w11 = w[4], w12 = w[5];
    const float w20 = w[6], w21 = w[7], w22 = w[8];
    const float q0 = bias[0], q1 = bias[1], q2 = bias[2];

    const float* __restrict__ xp = x   + (size_t)b * (SEQ * FDIM) + f;
    float*       __restrict__ op = out + (size_t)b * (SEQ * FDIM) + f;

    // head: plain loads, consumed by the touch so the compiler's own waitcnt
    // lands HERE (before any asm loads are outstanding)
    float h0 = xp[0 * FDIM], h1 = xp[1 * FDIM], h2 = xp[2 * FDIM];
    asm volatile("" : "+v"(h0), "+v"(h1), "+v"(h2));
    ST1(h0, op, 0); ST1(h1, op, 256); ST1(h2, op, 512);   // 3 asm stores

    const float* xc = xp + 3 * FDIM;
    float*       oc = op + 3 * FDIM;

    DECL27(LA); DECL27(LB);     // load double-buffer (asm outputs)
    DECL27Z(OA); DECL27Z(OB);   // output/staging double-bank

    // seed state into OB tail (first even-group compute reads OB24..26)
    OB24 = h0; OB25 = h1; OB26 = h2;

    PF27(LA);                   // g0
    PF27(LB);                   // g1
    // outstanding: hst(3) LA(27) LB(27) = 57 -> vmcnt(27) retires hst + LA
    WAITVM(27, LA, OA);

    // loop t: computes g=2t (LA,OA) and g=2t+1 (LB,OB); prefetches 2t+2, 2t+3
    #pragma unroll 1
    for (int t = 0; t < 54; ++t) {
        COMPUTE_GRP(LA, OA, OB24, OB25, OB26);   // g = 2t
        PF27(LA);                                 // g = 2t+2
        // young 54 = st(2t)(27) + LA(2t+2)(27): LB(2t+1) ready, OB st(2t-1) retired
        WAITVM(54, LB, OB);
        COMPUTE_GRP(LB, OB, OA24, OA25, OA26);   // g = 2t+1
        PF27(LB);                                 // g = 2t+3
        // young 54 = st(2t+1)(27) + LB(2t+3)(27): LA(2t+2) ready, OA st(2t) retired
        WAITVM(54, LA, OA);
    }

    // epilogue: g108 (in LA), g109 (in LB), g110
    COMPUTE_GRP(LA, OA, OB24, OB25, OB26);       // g108
    PF27(LA);                                     // g110
    WAITVM(54, LB, OB);                           // LB=g109 ready; OB st(107) retired
    COMPUTE_GRP(LB, OB, OA24, OA25, OA26);       // g109
    WAITVM(27, LA, OA);                           // LA=g110 ready; OA st(108) retired
    COMPUTE_GRP(LA, OA, OB24, OB25, OB26);       // g110
}

extern "C" void kernel_launch(void* const* d_in, const int* in_sizes, int n_in,
                              void* d_out, int out_size, void* d_ws, size_t ws_size,
                              hipStream_t stream) {
    const float* x    = (const float*)d_in[0];
    const float* w    = (const float*)d_in[1];
    const float* bias = (const float*)d_in[2];
    float* out        = (float*)d_out;

    hipLaunchKernelGGL(scan_kernel, dim3(128), dim3(FDIM), 0, stream,
                       x, w, bias, out);
}